// Round 5
// baseline (238.664 us; speedup 1.0000x reference)
//
#include <hip/hip_runtime.h>
#include <hip/hip_fp16.h>
#include <math.h>

// CTC forward loss (warp-ctc semantics). T=1024, B=64, V=128, L=256, S=513.
//
// Round 5:
//  - DP: 8 batches per block (512 thr = 8 waves, wave w -> batch blk*8+w).
//    2 waves/SIMD so issue slots left idle by one wave's dependent-latency
//    stalls are filled by the sibling wave (m114 co-scheduling). Waves are
//    fully independent: no barriers, no LDS; DPP is wave-local.
//  - Probs: raw v_exp_f32/v_log_f32 builtins (no libm denormal fixup code).

#define L2E 1.4426950408889634f
#define LN2 0.6931471805599453f

constexpr int T  = 1024;
constexpr int B  = 64;
constexpr int V  = 128;
constexpr int L  = 256;
constexpr int R  = 260;        // fp16 elems per P row: [256 labels][blank][pad]
constexpr int TP = T + 32;     // padded time rows per batch

#if __has_builtin(__builtin_amdgcn_exp2f)
#define FEXP2(x) __builtin_amdgcn_exp2f(x)
#else
#define FEXP2(x) exp2f(x)
#endif
#if __has_builtin(__builtin_amdgcn_log2f)
#define FLOG2(x) __builtin_amdgcn_log2f(x)
#else
#define FLOG2(x) log2f(x)
#endif

// ---- DPP helpers (gfx9 ctrl: 0x111+N row_shr, 0x138 wave_shr:1,
//      0x142 row_bcast15, 0x143 row_bcast31) ----
template <int CTRL>
__device__ __forceinline__ float fdpp0(float x) {        // invalid lanes -> 0
  return __int_as_float(__builtin_amdgcn_update_dpp(
      0, __float_as_int(x), CTRL, 0xf, 0xf, true));
}
template <int CTRL>
__device__ __forceinline__ float fdppk(float x) {        // invalid lanes -> keep
  return __int_as_float(__builtin_amdgcn_update_dpp(
      __float_as_int(x), __float_as_int(x), CTRL, 0xf, 0xf, false));
}

__device__ __forceinline__ float wave_bcast63(float x) {
  return __int_as_float(__builtin_amdgcn_readlane(__float_as_int(x), 63));
}

__device__ __forceinline__ float wave_max(float x) {
  x = fmaxf(x, fdppk<0x111>(x));
  x = fmaxf(x, fdppk<0x112>(x));
  x = fmaxf(x, fdppk<0x114>(x));
  x = fmaxf(x, fdppk<0x118>(x));
  x = fmaxf(x, fdppk<0x142>(x));
  x = fmaxf(x, fdppk<0x143>(x));
  return wave_bcast63(x);
}
__device__ __forceinline__ float wave_sum_nn(float x) {  // x >= 0
  x += fdpp0<0x111>(x);
  x += fdpp0<0x112>(x);
  x += fdpp0<0x114>(x);
  x += fdpp0<0x118>(x);
  x += fdpp0<0x142>(x);
  x += fdpp0<0x143>(x);
  return wave_bcast63(x);
}

// ---------------- prologue: emission probabilities ----------------
__global__ __launch_bounds__(256) void ctc_probs_kernel(
    const float* __restrict__ acts,        // (T, B, V)
    const int* __restrict__ labels,        // (B, L)
    ushort* __restrict__ P) {              // (B, TP, R) fp16 bits
  const int w    = threadIdx.x >> 6;
  const int lane = threadIdx.x & 63;
  const int t    = blockIdx.x * 4 + w;     // t in [0, TP)
  const int b    = blockIdx.y;
  ushort* prow = P + ((size_t)b * TP + t) * R;

  if (t >= T) {                            // zero pad rows past t=T-1
    uint2 z; z.x = 0u; z.y = 0u;
    *(uint2*)(prow + 4 * lane) = z;
    if (lane == 0) *(uint2*)(prow + 256) = z;
    return;
  }

  const float* row = acts + ((size_t)t * B + b) * V;
  const float2 v2 = *(const float2*)(row + 2 * lane);
  const float mx  = wave_max(fmaxf(v2.x, v2.y));
  const float mx2 = mx * L2E;
  float sm = FEXP2(fmaf(v2.x, L2E, -mx2)) + FEXP2(fmaf(v2.y, L2E, -mx2));
  sm = wave_sum_nn(sm);
  const float den2 = mx2 + FLOG2(sm);

  const int4 lv = *(const int4*)(labels + (size_t)b * L + 4 * lane);
  const float p0 = FEXP2(fmaf(row[lv.x], L2E, -den2));
  const float p1 = FEXP2(fmaf(row[lv.y], L2E, -den2));
  const float p2 = FEXP2(fmaf(row[lv.z], L2E, -den2));
  const float p3 = FEXP2(fmaf(row[lv.w], L2E, -den2));
  uint2 u;
  u.x = (uint)__half_as_ushort(__float2half_rn(p0)) |
        ((uint)__half_as_ushort(__float2half_rn(p1)) << 16);
  u.y = (uint)__half_as_ushort(__float2half_rn(p2)) |
        ((uint)__half_as_ushort(__float2half_rn(p3)) << 16);
  *(uint2*)(prow + 4 * lane) = u;
  if (lane == 0) {
    const float pb = FEXP2(fmaf(row[0], L2E, -den2));
    prow[256] = __half_as_ushort(__float2half_rn(pb));
  }
}

// ---------------- DP kernel: 8 waves/block, one batch per wave ----------------
__device__ __forceinline__ float h2f(uint bits) {
  return __half2float(__ushort_as_half((ushort)bits));
}

__global__ __launch_bounds__(512) void ctc_dp_kernel(
    const ushort* __restrict__ P,
    const int* __restrict__ labels,
    const int* __restrict__ act_lens,
    const int* __restrict__ label_lens,
    float* __restrict__ out) {
  const int wave = threadIdx.x >> 6;
  const int lane = threadIdx.x & 63;
  const int b    = blockIdx.x * 8 + wave;
  const ushort* __restrict__ Pb = P + (size_t)b * TP * R;

  // skip-transition flags for the 4 odd cells (labels 4l..4l+3)
  const int4 lv   = *(const int4*)(labels + (size_t)b * L + 4 * lane);
  const int prevw = __builtin_amdgcn_update_dpp(0, lv.w, 0x138, 0xf, 0xf, true);
  const float f0 = (lane > 0 && lv.x != 0 && lv.x != prevw) ? 1.f : 0.f;
  const float f1 = (lv.y != 0 && lv.y != lv.x) ? 1.f : 0.f;
  const float f2 = (lv.z != 0 && lv.z != lv.y) ? 1.f : 0.f;
  const float f3 = (lv.w != 0 && lv.w != lv.z) ? 1.f : 0.f;

  const int AL = act_lens[b];

  // ---- t=0 init (linear domain; unreachable cells = 0) ----
  float a0=0.f,a1=0.f,a2=0.f,a3=0.f,a4=0.f,a5=0.f,a6=0.f,a7=0.f,a8=0.f;
  {
    const uint2 u0 = *(const uint2*)(Pb + 4 * lane);
    const float e00 = h2f(u0.x & 0xffffu);
    const float eb0 = h2f(Pb[256]);
    if (lane == 0) { a0 = eb0; a1 = e00; }
  }
  float acc = 0.f;   // accumulated log2 of renorm scales (wave-uniform)

  auto step = [&](uint2 u, uint ub) {
    const float pc7 = fdpp0<0x138>(a7);    // prev lane's a7 (lane0 -> 0)
    const float pc6 = fdpp0<0x138>(a6);
    const float e0  = h2f(u.x & 0xffffu);
    const float e1  = h2f(u.x >> 16);
    const float e2  = h2f(u.y & 0xffffu);
    const float e3  = h2f(u.y >> 16);
    const float emb = h2f(ub);
    a8 = (a8 + a7) * emb;                  // cell 512 (meaningful on lane 63)
    a7 = fmaf(f3, a5, a7 + a6) * e3;
    a6 = (a6 + a5) * emb;
    a5 = fmaf(f2, a3, a5 + a4) * e2;
    a4 = (a4 + a3) * emb;
    a3 = fmaf(f1, a1, a3 + a2) * e1;
    a2 = (a2 + a1) * emb;
    a1 = fmaf(f0, pc6, a1 + a0) * e0;
    a0 = (a0 + pc7) * emb;
  };

  auto stepg = [&](uint2 u, uint ub, bool live) {
    const float pc7 = fdpp0<0x138>(a7);
    const float pc6 = fdpp0<0x138>(a6);
    const float e0  = h2f(u.x & 0xffffu);
    const float e1  = h2f(u.x >> 16);
    const float e2  = h2f(u.y & 0xffffu);
    const float e3  = h2f(u.y >> 16);
    const float emb = h2f(ub);
    const float n8 = (a8 + a7) * emb;
    const float n7 = fmaf(f3, a5, a7 + a6) * e3;
    const float n6 = (a6 + a5) * emb;
    const float n5 = fmaf(f2, a3, a5 + a4) * e2;
    const float n4 = (a4 + a3) * emb;
    const float n3 = fmaf(f1, a1, a3 + a2) * e1;
    const float n2 = (a2 + a1) * emb;
    const float n1 = fmaf(f0, pc6, a1 + a0) * e0;
    const float n0 = (a0 + pc7) * emb;
    if (live) { a8=n8; a7=n7; a6=n6; a5=n5; a4=n4; a3=n3; a2=n2; a1=n1; a0=n0; }
  };

  auto renorm = [&]() {
    float m = fmaxf(fmaxf(fmaxf(a0, a1), fmaxf(a2, a3)),
                    fmaxf(fmaxf(a4, a5), fmaxf(a6, a7)));
    m = fmaxf(m, a8);
    m = wave_max(m);
    // power-of-2 scale from exponent bits: r = 2^(127-e), exact
    int e = (int)((__float_as_uint(m) >> 23) & 0xffu);
    e = (e < 1) ? 1 : e;
    const float r = __uint_as_float((uint)(254 - e) << 23);
    acc += (float)(e - 127);
    a0*=r; a1*=r; a2*=r; a3*=r; a4*=r; a5*=r; a6*=r; a7*=r; a8*=r;
  };

  // ---- emission prefetch pipeline: depth 16 (rows t .. t+15) ----
  uint2 ev[16];
  uint  eb[16];
  #pragma unroll
  for (int k = 0; k < 16; ++k) {
    const ushort* pr = Pb + (size_t)(1 + k) * R;
    ev[k] = *(const uint2*)(pr + 4 * lane);
    eb[k] = pr[256];
  }

  const ushort* pf = Pb + (size_t)17 * R;  // row t+16 for t=1
  int t = 1;
  for (int blk = 0; blk < 64; ++blk) {     // 64 x 16 = steps t=1..1024
    const bool fast = (t + 16 <= AL);
    if (fast) {
      #pragma unroll
      for (int k = 0; k < 16; ++k) {
        const uint2 u = ev[k]; const uint ub = eb[k];
        const ushort* pr = pf + (size_t)k * R;       // row t+k+16 (pad-safe)
        ev[k] = *(const uint2*)(pr + 4 * lane);
        eb[k] = pr[256];
        step(u, ub);
        if (k == 7) renorm();
      }
    } else {
      #pragma unroll
      for (int k = 0; k < 16; ++k) {
        const uint2 u = ev[k]; const uint ub = eb[k];
        const ushort* pr = pf + (size_t)k * R;
        ev[k] = *(const uint2*)(pr + 4 * lane);
        eb[k] = pr[256];
        stepg(u, ub, (t + k) < AL);
        if (k == 7) renorm();
      }
    }
    t += 16;
    pf += (size_t)16 * R;
    renorm();
  }

  // ---- epilogue: -ln( (a[end] + a[end-1]) * 2^acc ) ----
  const int end  = 2 * label_lens[b];
  const int base = 8 * lane;
  float sel = 0.f;
  if (base     == end || base     == end - 1) sel += a0;
  if (base + 1 == end || base + 1 == end - 1) sel += a1;
  if (base + 2 == end || base + 2 == end - 1) sel += a2;
  if (base + 3 == end || base + 3 == end - 1) sel += a3;
  if (base + 4 == end || base + 4 == end - 1) sel += a4;
  if (base + 5 == end || base + 5 == end - 1) sel += a5;
  if (base + 6 == end || base + 6 == end - 1) sel += a6;
  if (base + 7 == end || base + 7 == end - 1) sel += a7;
  if (lane == 63 && (end == 512 || end - 1 == 512)) sel += a8;
  sel = wave_sum_nn(sel);
  if (lane == 0) {
    const float cost = -((FLOG2(sel) + acc) * LN2);
    atomicAdd(out, cost);
  }
}

extern "C" void kernel_launch(void* const* d_in, const int* in_sizes, int n_in,
                              void* d_out, int out_size, void* d_ws, size_t ws_size,
                              hipStream_t stream) {
  const float* acts       = (const float*)d_in[0];
  const int*   labels     = (const int*)d_in[1];
  const int*   act_lens   = (const int*)d_in[2];
  const int*   label_lens = (const int*)d_in[3];
  float* out = (float*)d_out;
  ushort* P  = (ushort*)d_ws;   // needs B*TP*R*2 = 35.1 MB

  hipMemsetAsync(out, 0, sizeof(float) * out_size, stream);
  ctc_probs_kernel<<<dim3(TP / 4, B), 256, 0, stream>>>(acts, labels, P);
  ctc_dp_kernel<<<B / 8, 512, 0, stream>>>(P, labels, act_lens, label_lens, out);
}

// Round 9
// 182.331 us; speedup vs baseline: 1.3090x; 1.3090x over previous
//
#include <hip/hip_runtime.h>
#include <hip/hip_fp16.h>
#include <math.h>

// CTC forward loss (warp-ctc semantics). T=1024, B=64, V=128, L=256, S=513.
//
// Round 9 = round 8 with tm = 0 (DIAGNOSTIC BISECT): forward wave does zero
// steps (alpha_0 = init), backward wave runs the full 1022 steps to B_1,
// combine P = alpha_0[0]*gamma_1[0] + alpha_0[1]*gamma_1[1]. This tests the
// backward machinery (wave_shl DPP, bstep, init, renorm) + combine end-to-end
// with everything else byte-identical to round 8.
//  pass            -> backward+combine correct; bug is in tm!=0 boundary logic
//  fail ~65536     -> per-backward-step systematic (error scales with steps)
//  fail ~32768     -> count-independent init/boundary bug

#define L2E 1.4426950408889634f
#define LN2 0.6931471805599453

constexpr int T   = 1024;
constexpr int B   = 64;
constexpr int V   = 128;
constexpr int L   = 256;
constexpr int S   = 2 * L + 1;   // 513
constexpr int R   = 260;         // fp16 elems per P row: [256 labels][blank][pad]
constexpr int PAD = 16;          // front AND back zero-pad rows
constexpr int TP  = T + 2 * PAD; // rows per batch in P

#if __has_builtin(__builtin_amdgcn_exp2f)
#define FEXP2(x) __builtin_amdgcn_exp2f(x)
#else
#define FEXP2(x) exp2f(x)
#endif
#if __has_builtin(__builtin_amdgcn_log2f)
#define FLOG2(x) __builtin_amdgcn_log2f(x)
#else
#define FLOG2(x) log2f(x)
#endif

// ---- DPP helpers (gfx9 ctrl: 0x111+N row_shr, 0x130 wave_shl:1,
//      0x138 wave_shr:1, 0x142 row_bcast15, 0x143 row_bcast31) ----
template <int CTRL>
__device__ __forceinline__ float fdpp0(float x) {        // invalid lanes -> 0
  return __int_as_float(__builtin_amdgcn_update_dpp(
      0, __float_as_int(x), CTRL, 0xf, 0xf, true));
}
template <int CTRL>
__device__ __forceinline__ float fdppk(float x) {        // invalid lanes -> keep
  return __int_as_float(__builtin_amdgcn_update_dpp(
      __float_as_int(x), __float_as_int(x), CTRL, 0xf, 0xf, false));
}

__device__ __forceinline__ float wave_bcast63(float x) {
  return __int_as_float(__builtin_amdgcn_readlane(__float_as_int(x), 63));
}

__device__ __forceinline__ float wave_max(float x) {
  x = fmaxf(x, fdppk<0x111>(x));
  x = fmaxf(x, fdppk<0x112>(x));
  x = fmaxf(x, fdppk<0x114>(x));
  x = fmaxf(x, fdppk<0x118>(x));
  x = fmaxf(x, fdppk<0x142>(x));
  x = fmaxf(x, fdppk<0x143>(x));
  return wave_bcast63(x);
}
__device__ __forceinline__ float wave_sum_nn(float x) {  // x >= 0
  x += fdpp0<0x111>(x);
  x += fdpp0<0x112>(x);
  x += fdpp0<0x114>(x);
  x += fdpp0<0x118>(x);
  x += fdpp0<0x142>(x);
  x += fdpp0<0x143>(x);
  return wave_bcast63(x);
}

__device__ __forceinline__ float h2f(uint bits) {
  return __half2float(__ushort_as_half((ushort)bits));
}

// ---------------- prologue: emission probabilities ----------------
__global__ __launch_bounds__(256) void ctc_probs_kernel(
    const float* __restrict__ acts,        // (T, B, V)
    const int* __restrict__ labels,        // (B, L)
    ushort* __restrict__ P) {              // (B, TP, R) fp16 bits
  const int w    = threadIdx.x >> 6;
  const int lane = threadIdx.x & 63;
  const int ri   = blockIdx.x * 4 + w;     // row index in [0, TP)
  const int b    = blockIdx.y;
  ushort* prow = P + ((size_t)b * TP + ri) * R;

  if (ri < PAD || ri >= PAD + T) {         // zero pad rows (front & back)
    uint2 z; z.x = 0u; z.y = 0u;
    *(uint2*)(prow + 4 * lane) = z;
    if (lane == 0) *(uint2*)(prow + 256) = z;
    return;
  }
  const int t = ri - PAD;

  const float* row = acts + ((size_t)t * B + b) * V;
  const float2 v2 = *(const float2*)(row + 2 * lane);
  const float mx  = wave_max(fmaxf(v2.x, v2.y));
  const float mx2 = mx * L2E;
  float sm = FEXP2(fmaf(v2.x, L2E, -mx2)) + FEXP2(fmaf(v2.y, L2E, -mx2));
  sm = wave_sum_nn(sm);
  const float den2 = mx2 + FLOG2(sm);

  const int4 lv = *(const int4*)(labels + (size_t)b * L + 4 * lane);
  const float p0 = FEXP2(fmaf(row[lv.x], L2E, -den2));
  const float p1 = FEXP2(fmaf(row[lv.y], L2E, -den2));
  const float p2 = FEXP2(fmaf(row[lv.z], L2E, -den2));
  const float p3 = FEXP2(fmaf(row[lv.w], L2E, -den2));
  uint2 u;
  u.x = (uint)__half_as_ushort(__float2half_rn(p0)) |
        ((uint)__half_as_ushort(__float2half_rn(p1)) << 16);
  u.y = (uint)__half_as_ushort(__float2half_rn(p2)) |
        ((uint)__half_as_ushort(__float2half_rn(p3)) << 16);
  *(uint2*)(prow + 4 * lane) = u;
  if (lane == 0) {
    const float pb = FEXP2(fmaf(row[0], L2E, -den2));
    prow[256] = __half_as_ushort(__float2half_rn(pb));
  }
}

// ---------------- DP kernel: 2 waves/block (fwd + bwd), one batch/block ----
__global__ __launch_bounds__(128) void ctc_dp_kernel(
    const ushort* __restrict__ P,
    const int* __restrict__ labels,
    const int* __restrict__ act_lens,
    const int* __restrict__ label_lens,
    float* __restrict__ out) {
  const int b    = blockIdx.x;
  const int wave = threadIdx.x >> 6;
  const int lane = threadIdx.x & 63;
  // Pb points at logical row t=0 (front pad rows at negative indices)
  const ushort* __restrict__ Pb = P + (size_t)b * TP * R + (size_t)PAD * R;

  __shared__ __align__(16) float sh_alpha[S];
  __shared__ float sh_accA;

  const int4 lv = *(const int4*)(labels + (size_t)b * L + 4 * lane);
  const int AL  = act_lens[b];
  const int tm  = 0;                       // DIAGNOSTIC: full-backward bisect

  uint2 ev[16];
  uint  eb[16];
  float acc = 0.f;                          // per-wave log2 scale accumulator
  // backward-wave outputs (gamma_{tm+1} pieces), live across the barrier
  float gm0=0.f,gm1=0.f,gm2=0.f,gm3=0.f,gm4=0.f,gm5=0.f,gm6=0.f,gm7=0.f,gB8=0.f;
  const float m63 = (lane == 63) ? 1.f : 0.f;

  if (wave == 0) {
    // ================= forward: alpha t=0..tm =================
    const int prevw = __builtin_amdgcn_update_dpp(0, lv.w, 0x138, 0xf, 0xf, true);
    const float f0 = (lane > 0 && lv.x != 0 && lv.x != prevw) ? 1.f : 0.f;
    const float f1 = (lv.y != 0 && lv.y != lv.x) ? 1.f : 0.f;
    const float f2 = (lv.z != 0 && lv.z != lv.y) ? 1.f : 0.f;
    const float f3 = (lv.w != 0 && lv.w != lv.z) ? 1.f : 0.f;

    float a0=0.f,a1=0.f,a2=0.f,a3=0.f,a4=0.f,a5=0.f,a6=0.f,a7=0.f,a8=0.f;
    {
      const uint2 u0 = *(const uint2*)(Pb + 4 * lane);
      const float e00 = h2f(u0.x & 0xffffu);
      const float eb0 = h2f(Pb[256]);
      if (lane == 0) { a0 = eb0; a1 = e00; }
    }

    auto step = [&](uint2 u, uint ub) {
      const float pc7 = fdpp0<0x138>(a7);  // prev lane's a7 = cell 8l-1
      const float e0  = h2f(u.x & 0xffffu);
      const float e1  = h2f(u.x >> 16);
      const float e2  = h2f(u.y & 0xffffu);
      const float e3  = h2f(u.y >> 16);
      const float emb = h2f(ub);
      a8 = (a8 + a7) * emb;
      a7 = fmaf(f3, a5, a7 + a6) * e3;
      a6 = (a6 + a5) * emb;
      a5 = fmaf(f2, a3, a5 + a4) * e2;
      a4 = (a4 + a3) * emb;
      a3 = fmaf(f1, a1, a3 + a2) * e1;
      a2 = (a2 + a1) * emb;
      a1 = fmaf(f0, pc7, a1 + a0) * e0;    // skip source = cell 8l-1 (pc7)
      a0 = (a0 + pc7) * emb;
    };
    auto stepg = [&](uint2 u, uint ub, bool live) {
      const float pc7 = fdpp0<0x138>(a7);
      const float e0  = h2f(u.x & 0xffffu);
      const float e1  = h2f(u.x >> 16);
      const float e2  = h2f(u.y & 0xffffu);
      const float e3  = h2f(u.y >> 16);
      const float emb = h2f(ub);
      const float n8 = (a8 + a7) * emb;
      const float n7 = fmaf(f3, a5, a7 + a6) * e3;
      const float n6 = (a6 + a5) * emb;
      const float n5 = fmaf(f2, a3, a5 + a4) * e2;
      const float n4 = (a4 + a3) * emb;
      const float n3 = fmaf(f1, a1, a3 + a2) * e1;
      const float n2 = (a2 + a1) * emb;
      const float n1 = fmaf(f0, pc7, a1 + a0) * e0;
      const float n0 = (a0 + pc7) * emb;
      if (live) { a8=n8; a7=n7; a6=n6; a5=n5; a4=n4; a3=n3; a2=n2; a1=n1; a0=n0; }
    };
    auto renorm = [&]() {
      float m = fmaxf(fmaxf(fmaxf(a0, a1), fmaxf(a2, a3)),
                      fmaxf(fmaxf(a4, a5), fmaxf(a6, a7)));
      m = fmaxf(m, a8);
      m = wave_max(m);
      int e = (int)((__float_as_uint(m) >> 23) & 0xffu);
      e = (e < 1) ? 1 : e;
      const float r = __uint_as_float((uint)(254 - e) << 23);
      acc += (float)(e - 127);
      a0*=r; a1*=r; a2*=r; a3*=r; a4*=r; a5*=r; a6*=r; a7*=r; a8*=r;
    };

    #pragma unroll
    for (int k = 0; k < 16; ++k) {         // preload rows 1..16
      const ushort* pr = Pb + (size_t)(1 + k) * R;
      ev[k] = *(const uint2*)(pr + 4 * lane);
      eb[k] = pr[256];
    }

    const int chunks = (tm + 15) >> 4;     // steps t=1..tm (0 chunks when tm=0)
    int t = 1;
    for (int c = 0; c < chunks; ++c) {
      if (t + 15 <= tm) {
        #pragma unroll
        for (int k = 0; k < 16; ++k) {
          const uint2 u = ev[k]; const uint ub = eb[k];
          const ushort* pr = Pb + (size_t)(t + k + 16) * R;
          ev[k] = *(const uint2*)(pr + 4 * lane);
          eb[k] = pr[256];
          step(u, ub);
          if (k == 7) renorm();
        }
      } else {
        #pragma unroll
        for (int k = 0; k < 16; ++k) {
          const uint2 u = ev[k]; const uint ub = eb[k];
          const ushort* pr = Pb + (size_t)(t + k + 16) * R;
          ev[k] = *(const uint2*)(pr + 4 * lane);
          eb[k] = pr[256];
          stepg(u, ub, (t + k) <= tm);
          if (k == 7) renorm();
        }
      }
      t += 16;
      renorm();
    }

    // hand alpha_tm (+scale) to the backward wave
    float4* sa = (float4*)sh_alpha;
    sa[2 * lane]     = make_float4(a0, a1, a2, a3);
    sa[2 * lane + 1] = make_float4(a4, a5, a6, a7);
    if (lane == 63) sh_alpha[512] = a8;
    if (lane == 0)  sh_accA = acc;
  } else {
    // ================= backward: beta t=AL-1..tm+1 =================
    const int nx = __builtin_amdgcn_update_dpp(0, lv.x, 0x130, 0xf, 0xf, true);
    const float g0 = (lv.y != 0 && lv.y != lv.x) ? 1.f : 0.f;  // cell 8l+1
    const float g1 = (lv.z != 0 && lv.z != lv.y) ? 1.f : 0.f;  // cell 8l+3
    const float g2 = (lv.w != 0 && lv.w != lv.z) ? 1.f : 0.f;  // cell 8l+5
    const float g3 = (nx   != 0 && nx   != lv.w) ? 1.f : 0.f;  // cell 8l+7
    const int end = 2 * label_lens[b];

    float b0,b1,b2,b3,b4,b5,b6,b7,b8;
    {
      // init at t = AL-1: B[s] = e[s] * I[s in {end, end-1}]
      const ushort* pr = Pb + (size_t)(AL - 1) * R;
      const uint2 u0 = *(const uint2*)(pr + 4 * lane);
      const float e0  = h2f(u0.x & 0xffffu);
      const float e1  = h2f(u0.x >> 16);
      const float e2  = h2f(u0.y & 0xffffu);
      const float e3  = h2f(u0.y >> 16);
      const float emb = h2f(pr[256]);
      const int base = 8 * lane;
      b0 = (base     == end || base     == end - 1) ? emb : 0.f;
      b1 = (base + 1 == end || base + 1 == end - 1) ? e0  : 0.f;
      b2 = (base + 2 == end || base + 2 == end - 1) ? emb : 0.f;
      b3 = (base + 3 == end || base + 3 == end - 1) ? e1  : 0.f;
      b4 = (base + 4 == end || base + 4 == end - 1) ? emb : 0.f;
      b5 = (base + 5 == end || base + 5 == end - 1) ? e2  : 0.f;
      b6 = (base + 6 == end || base + 6 == end - 1) ? emb : 0.f;
      b7 = (base + 7 == end || base + 7 == end - 1) ? e3  : 0.f;
      b8 = (512 == end) ? emb : 0.f;       // wave-uniform
    }

    auto bstep = [&](uint2 u, uint ub) {
      float pn0 = fdpp0<0x130>(b0);        // next lane's b0 (lane63 -> 0)
      pn0 = fmaf(m63, b8, pn0);            // lane63: cell 512 = own b8
      const float pn1 = fdpp0<0x130>(b1);
      const float e0  = h2f(u.x & 0xffffu);
      const float e1  = h2f(u.x >> 16);
      const float e2  = h2f(u.y & 0xffffu);
      const float e3  = h2f(u.y >> 16);
      const float emb = h2f(ub);
      b0 = (b0 + b1) * emb;
      b1 = fmaf(g0, b3, b1 + b2) * e0;
      b2 = (b2 + b3) * emb;
      b3 = fmaf(g1, b5, b3 + b4) * e1;
      b4 = (b4 + b5) * emb;
      b5 = fmaf(g2, b7, b5 + b6) * e2;
      b6 = (b6 + b7) * emb;
      b7 = fmaf(g3, pn1, b7 + pn0) * e3;
      b8 = b8 * emb;
    };
    auto bstepg = [&](uint2 u, uint ub, bool live) {
      float pn0 = fdpp0<0x130>(b0);
      pn0 = fmaf(m63, b8, pn0);
      const float pn1 = fdpp0<0x130>(b1);
      const float e0  = h2f(u.x & 0xffffu);
      const float e1  = h2f(u.x >> 16);
      const float e2  = h2f(u.y & 0xffffu);
      const float e3  = h2f(u.y >> 16);
      const float emb = h2f(ub);
      const float n0 = (b0 + b1) * emb;
      const float n1 = fmaf(g0, b3, b1 + b2) * e0;
      const float n2 = (b2 + b3) * emb;
      const float n3 = fmaf(g1, b5, b3 + b4) * e1;
      const float n4 = (b4 + b5) * emb;
      const float n5 = fmaf(g2, b7, b5 + b6) * e2;
      const float n6 = (b6 + b7) * emb;
      const float n7 = fmaf(g3, pn1, b7 + pn0) * e3;
      const float n8 = b8 * emb;
      if (live) { b0=n0; b1=n1; b2=n2; b3=n3; b4=n4; b5=n5; b6=n6; b7=n7; b8=n8; }
    };
    auto brenorm = [&]() {
      float m = fmaxf(fmaxf(fmaxf(b0, b1), fmaxf(b2, b3)),
                      fmaxf(fmaxf(b4, b5), fmaxf(b6, b7)));
      m = fmaxf(m, b8);
      m = wave_max(m);
      int e = (int)((__float_as_uint(m) >> 23) & 0xffu);
      e = (e < 1) ? 1 : e;
      const float r = __uint_as_float((uint)(254 - e) << 23);
      acc += (float)(e - 127);
      b0*=r; b1*=r; b2*=r; b3*=r; b4*=r; b5*=r; b6*=r; b7*=r; b8*=r;
    };

    #pragma unroll
    for (int k = 0; k < 16; ++k) {         // preload rows AL-2 .. AL-17
      const ushort* pr = Pb + (ptrdiff_t)(AL - 2 - k) * R;
      ev[k] = *(const uint2*)(pr + 4 * lane);
      eb[k] = pr[256];
    }

    const int tmp1 = tm + 1;
    const int NB = AL - 2 - tm;            // steps t = AL-2 down to tm+1
    const int chunksB = (NB + 15) >> 4;
    int t = AL - 2;
    for (int c = 0; c < chunksB; ++c) {
      if (t - 15 >= tmp1) {
        #pragma unroll
        for (int k = 0; k < 16; ++k) {
          const uint2 u = ev[k]; const uint ub = eb[k];
          int rpf = t - k - 16; rpf = (rpf < -PAD) ? -PAD : rpf;
          const ushort* pr = Pb + (ptrdiff_t)rpf * R;
          ev[k] = *(const uint2*)(pr + 4 * lane);
          eb[k] = pr[256];
          bstep(u, ub);
          if (k == 7) brenorm();
        }
      } else {
        #pragma unroll
        for (int k = 0; k < 16; ++k) {
          const uint2 u = ev[k]; const uint ub = eb[k];
          int rpf = t - k - 16; rpf = (rpf < -PAD) ? -PAD : rpf;
          const ushort* pr = Pb + (ptrdiff_t)rpf * R;
          ev[k] = *(const uint2*)(pr + 4 * lane);
          eb[k] = pr[256];
          bstepg(u, ub, (t - k) >= tmp1);
          if (k == 7) brenorm();
        }
      }
      t -= 16;
      brenorm();
    }

    // gamma_{tm+1}[s] = B[s] + B[s+1] + g(s)*B[s+2]
    float pn0 = fdpp0<0x130>(b0);
    pn0 = fmaf(m63, b8, pn0);
    const float pn1 = fdpp0<0x130>(b1);
    gm0 = b0 + b1;
    gm1 = fmaf(g0, b3, b1 + b2);
    gm2 = b2 + b3;
    gm3 = fmaf(g1, b5, b3 + b4);
    gm4 = b4 + b5;
    gm5 = fmaf(g2, b7, b5 + b6);
    gm6 = b6 + b7;
    gm7 = fmaf(g3, pn1, b7 + pn0);
    gB8 = b8;                              // gamma[512] = B[512]
  }

  __syncthreads();                         // convergent barrier (both waves)

  if (wave == 1) {
    const float4 A0 = ((const float4*)sh_alpha)[2 * lane];
    const float4 A1 = ((const float4*)sh_alpha)[2 * lane + 1];
    double d = (double)gm0 * A0.x + (double)gm1 * A0.y
             + (double)gm2 * A0.z + (double)gm3 * A0.w
             + (double)gm4 * A1.x + (double)gm5 * A1.y
             + (double)gm6 * A1.z + (double)gm7 * A1.w;
    if (lane == 63) d += (double)gB8 * (double)sh_alpha[512];
    #pragma unroll
    for (int off = 1; off < 64; off <<= 1) d += __shfl_xor(d, off);
    if (lane == 0) {
      if (!(d > 0.0)) d = 5e-324;          // never emit inf/nan
      const double l2 = log2(d) + (double)acc + (double)sh_accA;
      atomicAdd(out, (float)(-l2 * LN2));
    }
  }
}

extern "C" void kernel_launch(void* const* d_in, const int* in_sizes, int n_in,
                              void* d_out, int out_size, void* d_ws, size_t ws_size,
                              hipStream_t stream) {
  const float* acts       = (const float*)d_in[0];
  const int*   labels     = (const int*)d_in[1];
  const int*   act_lens   = (const int*)d_in[2];
  const int*   label_lens = (const int*)d_in[3];
  float* out = (float*)d_out;
  ushort* P  = (ushort*)d_ws;   // needs B*TP*R*2 = 35.1 MB

  hipMemsetAsync(out, 0, sizeof(float) * out_size, stream);
  ctc_probs_kernel<<<dim3(TP / 4, B), 256, 0, stream>>>(acts, labels, P);
  ctc_dp_kernel<<<B, 128, 0, stream>>>(P, labels, act_lens, label_lens, out);
}